// Round 16
// baseline (107.569 us; speedup 1.0000x reference)
//
#include <hip/hip_runtime.h>
#include <hip/hip_bf16.h>
#include <math.h>

#define B_    8
#define N_    9225
#define M_    4096
#define K_    32
#define HID_  64
#define DOUT_ 16

typedef __attribute__((ext_vector_type(8))) short short8;
typedef __attribute__((ext_vector_type(4))) float floatx4;
typedef __attribute__((ext_vector_type(4))) unsigned uint4v;

static __device__ __forceinline__ short f2bf(float f) {
    __hip_bfloat16 h = __float2bfloat16(f);
    return __builtin_bit_cast(short, h);
}
static __device__ __forceinline__ floatx4 splat4(float v) { return (floatx4){v, v, v, v}; }

// Scattered gather DIRECT to LDS: global source address is per-lane; LDS
// dest is the wave-uniform slab base -- HW writes base + lane*16.
static __device__ __forceinline__ void gload_lds16(const float* g, float* lds_base) {
    __builtin_amdgcn_global_load_lds(
        (const __attribute__((address_space(1))) void*)g,
        (__attribute__((address_space(3))) void*)lds_base, 16, 0, 0);
}

// Sum over each 16-lane DPP row via row_shr tree; lane (row*16+15) holds the sum.
static __device__ __forceinline__ float row16_sum(float v) {
    int t;
    t = __builtin_amdgcn_update_dpp(0, __builtin_bit_cast(int, v), 0x111, 0xF, 0xF, true);
    v += __builtin_bit_cast(float, t);
    t = __builtin_amdgcn_update_dpp(0, __builtin_bit_cast(int, v), 0x112, 0xF, 0xF, true);
    v += __builtin_bit_cast(float, t);
    t = __builtin_amdgcn_update_dpp(0, __builtin_bit_cast(int, v), 0x114, 0xF, 0xF, true);
    v += __builtin_bit_cast(float, t);
    t = __builtin_amdgcn_update_dpp(0, __builtin_bit_cast(int, v), 0x118, 0xF, 0xF, true);
    v += __builtin_bit_cast(float, t);
    return v;
}

// R27: residency attack in the new regime. R26 (rank-4 VALU layer-1, LUT
// gelu, slab-staged fv) = 101.7 best; per-phase issue work is now ~65 VALU
// + 2 MFMA => issue-bound estimate ~5us, yet it_kernel ~36us -- the 6-8x
// gap is latency amortized over only 3 waves/SIMD (launch_bounds(256,3),
// ~160 live regs incl ax[4][4]=64, 36KB LDS). R14's occupancy null was the
// OLD regime (compiler had sunk the pipeline into use-sites; more waves
// traded deeper per-wave stalls); the burst+slab structure holds pipeline
// state in LDS now, so the lever gets one re-test. Changes vs R26:
// (1) 2 rows/wave, 4096 blocks: raw/yv2/sw halve, ax -> [2][4] (32 regs),
//     stg -> 16KB (20KB total LDS, 8 blocks/CU headroom); est ~116 regs.
// (2) launch_bounds(256,4): 4 waves/SIMD, honest at this footprint.
// Everything else byte-identical to R26. Pre-commit: occupancy up AND time
// down => confirmed; null => residency lever exhausted, declare terminal
// next round; regression => setup duplication, revert R26.
__global__ __launch_bounds__(256, 4) void it_kernel(
    const float* __restrict__ y,
    const float* __restrict__ x,
    const float* __restrict__ f_y,
    const float* __restrict__ weights,
    const float* __restrict__ W1,   // [4][64] row-major
    const float* __restrict__ b1,   // [64]
    const float* __restrict__ W2,   // [64][16] row-major
    const float* __restrict__ b2,   // [16]
    const int*   __restrict__ nbr,  // [B][M][K] int32
    float*       __restrict__ out)  // [B][M][16]
{
    __shared__ unsigned short lut[2048];        // 4KB gelu table
    __shared__ float stg[4][4][256];            // 16KB: wave x phase x lane*4

    const int tid  = threadIdx.x;
    // ---- fill gelu LUT: exact erf-gelu, bf16 values. [-8,8], step 1/128 ----
    #pragma unroll
    for (int i = tid; i < 2048; i += 256) {
        const float xi = (float)(i - 1024) * 0.0078125f;
        const float g  = 0.5f * xi * (1.0f + erff(xi * 0.70710678f));
        lut[i] = (unsigned short)f2bf(g);
    }

    const int lane = tid & 63;
    const int q    = lane >> 4;    // quad 0..3
    const int nlo  = lane & 15;

    const int blk   = blockIdx.x;
    const int batch = blk & 7;          // XCD pin (round-robin heuristic)
    const int pblk  = blk >> 3;         // 0..511 within batch
    const int wid   = tid >> 6;         // wave 0..3
    const int row0  = __builtin_amdgcn_readfirstlane(batch * M_ + pblk * 8 + wid * 2);
    const int bbase = batch * N_;

    // ---- neighbor indices for all 4 phases: issue first ----
    int raw[4];
    #pragma unroll
    for (int ph = 0; ph < 4; ++ph) {
        const int it = ph >> 1, h = ph & 1;
        raw[ph] = nbr[(size_t)(row0 + it) * K_ + h * 16 + nlo];
    }

    // ---- layer-1 weight slices for this lane's 16 H-slots (H = 16t+4q+r):
    //      c0/c1 = 128*W1[0/1][H] (y coefficients, exact f32) ----
    floatx4 c0q[4], c1q[4];
    #pragma unroll
    for (int t = 0; t < 4; ++t) {
        c0q[t] = *(const floatx4*)(W1 + 0 * HID_ + t * 16 + q * 4) * 128.0f;
        c1q[t] = *(const floatx4*)(W1 + 1 * HID_ + t * 16 + q * 4) * 128.0f;
    }

    // ---- per-row x/b1 part of the LUT index, exact f32, 2 rows:
    //      ax[it][t] = 128*(x0*W1[2][H] + x1*W1[3][H] + b1[H]) + 1024.5 ----
    floatx4 ax[2][4];
    #pragma unroll
    for (int t = 0; t < 4; ++t) {
        const floatx4 w2v = *(const floatx4*)(W1 + 2 * HID_ + t * 16 + q * 4);
        const floatx4 w3v = *(const floatx4*)(W1 + 3 * HID_ + t * 16 + q * 4);
        const floatx4 b1v = *(const floatx4*)(b1 + t * 16 + q * 4);
        #pragma unroll
        for (int it = 0; it < 2; ++it) {
            const float2 xv = *(const float2*)(x + (size_t)(row0 + it) * 2);
            const floatx4 pre = __builtin_elementwise_fma(splat4(xv.x), w2v,
                                __builtin_elementwise_fma(splat4(xv.y), w3v, b1v));
            ax[it][t] = __builtin_elementwise_fma(pre, splat4(128.0f), splat4(1024.5f));
        }
    }

    // ---- W2 A-fragment with layer-1-layout re-index (R13-validated) ----
    short8 w2f[2];
    #pragma unroll
    for (int ch = 0; ch < 2; ++ch)
        #pragma unroll
        for (int jj = 0; jj < 8; ++jj) {
            const int H = (ch * 2 + (jj >> 2)) * 16 + q * 4 + (jj & 3);
            w2f[ch][jj] = f2bf(W2[H * DOUT_ + nlo]);
        }
    const floatx4 b2r = *(const floatx4*)(b2 + q * 4);

    // ---- BURST: fv -> LDS slab (no VGPR cost); y (all lanes, f32) + w -> regs ----
    float2 yv2[4]; float sw[4];
    #pragma unroll
    for (int P = 0; P < 4; ++P) {
        const int rv  = raw[P];
        const int vld = rv >= 0;
        const int bn  = bbase + (vld ? rv : 0);
        gload_lds16(f_y + (size_t)bn * 16 + q * 4, &stg[wid][P][0]);
        const float wv_ = weights[bn];
        sw[P] = vld ? wv_ : 0.0f;
        yv2[P] = *(const float2*)(y + (size_t)bn * 2);   // finite garbage if invalid; killed by sw=0
    }

    // Single drain: __syncthreads waits vmcnt(0)+lgkmcnt(0) (burst complete,
    // LUT visible). sched_barrier keeps compute below it.
    __syncthreads();
    __builtin_amdgcn_sched_barrier(0);

    float partial[4] = {0.f, 0.f, 0.f, 0.f};
    #pragma unroll
    for (int it = 0; it < 2; ++it) {
        const int pa = 2 * it, pb = 2 * it + 1;

        // fv slices for both half-phases (ds_read_b128, issued up front)
        const floatx4 fva = *(const floatx4*)&stg[wid][pa][lane * 4];
        const floatx4 fvb = *(const floatx4*)&stg[wid][pb][lane * 4];

        const float y0a = yv2[pa].x, y1a = yv2[pa].y;
        const float y0b = yv2[pb].x, y1b = yv2[pb].y;

        // ---- layer 1 (rank-4, exact f32): idx = y0*c0 + y1*c1 + ax;
        //      then clamp -> LUT -> pack. Two independent chains. ----
        unsigned hwa[8], hwb[8];
        #pragma unroll
        for (int t = 0; t < 4; ++t) {
            floatx4 ia = __builtin_elementwise_fma(splat4(y0a), c0q[t],
                         __builtin_elementwise_fma(splat4(y1a), c1q[t], ax[it][t]));
            floatx4 ib = __builtin_elementwise_fma(splat4(y0b), c0q[t],
                         __builtin_elementwise_fma(splat4(y1b), c1q[t], ax[it][t]));
            ia = __builtin_elementwise_min(
                     __builtin_elementwise_max(ia, splat4(0.0f)), splat4(2047.0f));
            ib = __builtin_elementwise_min(
                     __builtin_elementwise_max(ib, splat4(0.0f)), splat4(2047.0f));
            const unsigned short a0 = lut[(unsigned)ia[0]];
            const unsigned short a1 = lut[(unsigned)ia[1]];
            const unsigned short a2 = lut[(unsigned)ia[2]];
            const unsigned short a3 = lut[(unsigned)ia[3]];
            const unsigned short c0 = lut[(unsigned)ib[0]];
            const unsigned short c1 = lut[(unsigned)ib[1]];
            const unsigned short c2 = lut[(unsigned)ib[2]];
            const unsigned short c3 = lut[(unsigned)ib[3]];
            hwa[t * 2 + 0] = (unsigned)a0 | ((unsigned)a1 << 16);
            hwa[t * 2 + 1] = (unsigned)a2 | ((unsigned)a3 << 16);
            hwb[t * 2 + 0] = (unsigned)c0 | ((unsigned)c1 << 16);
            hwb[t * 2 + 1] = (unsigned)c2 | ((unsigned)c3 << 16);
        }
        const short8 hf0a = __builtin_bit_cast(short8, (uint4v){hwa[0], hwa[1], hwa[2], hwa[3]});
        const short8 hf1a = __builtin_bit_cast(short8, (uint4v){hwa[4], hwa[5], hwa[6], hwa[7]});
        const short8 hf0b = __builtin_bit_cast(short8, (uint4v){hwb[0], hwb[1], hwb[2], hwb[3]});
        const short8 hf1b = __builtin_bit_cast(short8, (uint4v){hwb[4], hwb[5], hwb[6], hwb[7]});

        // ---- layer 2: both chains interleaved (only MFMAs left) ----
        floatx4 acca = b2r, accb = b2r;
        acca = __builtin_amdgcn_mfma_f32_16x16x32_bf16(w2f[0], hf0a, acca, 0, 0, 0);
        accb = __builtin_amdgcn_mfma_f32_16x16x32_bf16(w2f[0], hf0b, accb, 0, 0, 0);
        acca = __builtin_amdgcn_mfma_f32_16x16x32_bf16(w2f[1], hf1a, acca, 0, 0, 0);
        accb = __builtin_amdgcn_mfma_f32_16x16x32_bf16(w2f[1], hf1b, accb, 0, 0, 0);

        // ---- accumulate both half-phases, reduce over 16 lanes, store row ----
        const float sa = sw[pa], sb = sw[pb];
        #pragma unroll
        for (int r = 0; r < 4; ++r) {
            partial[r] = fmaf(acca[r], fva[r] * sa, partial[r]);
            partial[r] = fmaf(accb[r], fvb[r] * sb, partial[r]);
        }
        #pragma unroll
        for (int r = 0; r < 4; ++r) partial[r] = row16_sum(partial[r]);
        if (nlo == 15) {
            floatx4 o = {partial[0], partial[1], partial[2], partial[3]};
            *(floatx4*)(out + (size_t)(row0 + it) * DOUT_ + q * 4) = o;
        }
        #pragma unroll
        for (int r = 0; r < 4; ++r) partial[r] = 0.f;
    }
}

extern "C" void kernel_launch(void* const* d_in, const int* in_sizes, int n_in,
                              void* d_out, int out_size, void* d_ws, size_t ws_size,
                              hipStream_t stream) {
    const float* y   = (const float*)d_in[0];
    const float* x   = (const float*)d_in[1];
    const float* f_y = (const float*)d_in[2];
    const float* w   = (const float*)d_in[3];
    const float* W1  = (const float*)d_in[4];
    const float* b1  = (const float*)d_in[5];
    const float* W2  = (const float*)d_in[6];
    const float* b2  = (const float*)d_in[7];
    const int*   nbr = (const int*)d_in[8];
    float* out = (float*)d_out;

    // Single dispatch. 4096 blocks: 512 per batch (8 rows/block),
    // batch = blk & 7 -> XCD pin.
    dim3 grid(B_ * M_ / 8), block(256);
    hipLaunchKernelGGL(it_kernel, grid, block, 0, stream,
                       y, x, f_y, w, W1, b1, W2, b2, nbr, out);
}

// Round 17
// 101.603 us; speedup vs baseline: 1.0587x; 1.0587x over previous
//
#include <hip/hip_runtime.h>
#include <hip/hip_bf16.h>
#include <math.h>

#define B_    8
#define N_    9225
#define M_    4096
#define K_    32
#define HID_  64
#define DOUT_ 16

typedef __attribute__((ext_vector_type(8))) short short8;
typedef __attribute__((ext_vector_type(4))) float floatx4;
typedef __attribute__((ext_vector_type(4))) unsigned uint4v;

static __device__ __forceinline__ short f2bf(float f) {
    __hip_bfloat16 h = __float2bfloat16(f);
    return __builtin_bit_cast(short, h);
}
static __device__ __forceinline__ floatx4 splat4(float v) { return (floatx4){v, v, v, v}; }

// Scattered gather DIRECT to LDS: global source address is per-lane; LDS
// dest is the wave-uniform slab base -- HW writes base + lane*16.
static __device__ __forceinline__ void gload_lds16(const float* g, float* lds_base) {
    __builtin_amdgcn_global_load_lds(
        (const __attribute__((address_space(1))) void*)g,
        (__attribute__((address_space(3))) void*)lds_base, 16, 0, 0);
}

// Sum over each 16-lane DPP row via row_shr tree; lane (row*16+15) holds the sum.
static __device__ __forceinline__ float row16_sum(float v) {
    int t;
    t = __builtin_amdgcn_update_dpp(0, __builtin_bit_cast(int, v), 0x111, 0xF, 0xF, true);
    v += __builtin_bit_cast(float, t);
    t = __builtin_amdgcn_update_dpp(0, __builtin_bit_cast(int, v), 0x112, 0xF, 0xF, true);
    v += __builtin_bit_cast(float, t);
    t = __builtin_amdgcn_update_dpp(0, __builtin_bit_cast(int, v), 0x114, 0xF, 0xF, true);
    v += __builtin_bit_cast(float, t);
    t = __builtin_amdgcn_update_dpp(0, __builtin_bit_cast(int, v), 0x118, 0xF, 0xF, true);
    v += __builtin_bit_cast(float, t);
    return v;
}

// R28 == R26 (verified session best, 101.7us), restored after R27's
// occupancy re-test regressed to 107.6 and CLOSED the ledger:
//  - R27 halved per-wave footprint (VGPR 64, LDS 20KB -> resources permit
//    ~8 waves/SIMD) yet OccupancyPercent stayed ~33% -- the ~30-36% reading
//    is invariant to resources all session; residency is scheduler-limited,
//    not resource-limited. Residency lever exhausted.
//  - Doubled blocks exposed the marginal setup cost (~3us: LUT fill +
//    c0q/c1q/ax + W2 frag) and scaled LUT bank conflicts (2.46M vs 1.86M).
// Session ledger (R12-R27), every axis measured: compute-only floor ~27-30us
// (R19 ablation), gathers ~7-10us; VALU +-30%, ILP x1/x2, MFMA 10->2/phase,
// addresses 144->80, phase geometry 16/32-col, reg footprint 40-170, burst/
// slab/sched_barrier, occupancy both regimes -- all within +-1us of
// it_kernel ~36us except the structural wins locked in here. Binder:
// per-eval chain latency x ~3 waves/SIMD scheduler residency. No HW counter
// saturated; this is the structure's verified optimum, not a HW roofline.
// Structure: 2048 blocks (XCD pin batch=blk&7), 4 rows/wave, burst gathers
// (fv via global_load_lds slab, y f32 all lanes, w per-lane), rank-4
// factorized exact-f32 layer-1 feeding an erf-gelu LDS LUT (idx = fma(y,c)
// +ax, scale/bias pre-folded), H-re-indexed W2 MFMA layer-2, dual-chain
// row pairs, DPP row16 reduce.
__global__ __launch_bounds__(256, 3) void it_kernel(
    const float* __restrict__ y,
    const float* __restrict__ x,
    const float* __restrict__ f_y,
    const float* __restrict__ weights,
    const float* __restrict__ W1,   // [4][64] row-major
    const float* __restrict__ b1,   // [64]
    const float* __restrict__ W2,   // [64][16] row-major
    const float* __restrict__ b2,   // [16]
    const int*   __restrict__ nbr,  // [B][M][K] int32
    float*       __restrict__ out)  // [B][M][16]
{
    __shared__ unsigned short lut[2048];        // 4KB gelu table
    __shared__ float stg[4][8][256];            // 32KB: wave x phase x lane*4

    const int tid  = threadIdx.x;
    // ---- fill gelu LUT: exact erf-gelu, bf16 values. [-8,8], step 1/128 ----
    #pragma unroll
    for (int i = tid; i < 2048; i += 256) {
        const float xi = (float)(i - 1024) * 0.0078125f;
        const float g  = 0.5f * xi * (1.0f + erff(xi * 0.70710678f));
        lut[i] = (unsigned short)f2bf(g);
    }

    const int lane = tid & 63;
    const int q    = lane >> 4;    // quad 0..3
    const int nlo  = lane & 15;

    const int blk   = blockIdx.x;
    const int batch = blk & 7;          // XCD pin (round-robin heuristic)
    const int pblk  = blk >> 3;         // 0..255 within batch
    const int wid   = tid >> 6;         // wave 0..3
    const int row0  = __builtin_amdgcn_readfirstlane(batch * M_ + pblk * 16 + wid * 4);
    const int bbase = batch * N_;

    // ---- neighbor indices for all 8 phases: issue first ----
    int raw[8];
    #pragma unroll
    for (int ph = 0; ph < 8; ++ph) {
        const int it = ph >> 1, h = ph & 1;
        raw[ph] = nbr[(size_t)(row0 + it) * K_ + h * 16 + nlo];
    }

    // ---- layer-1 weight slices for this lane's 16 H-slots (H = 16t+4q+r):
    //      c0/c1 = 128*W1[0/1][H] (y coefficients, exact f32) ----
    floatx4 c0q[4], c1q[4];
    #pragma unroll
    for (int t = 0; t < 4; ++t) {
        c0q[t] = *(const floatx4*)(W1 + 0 * HID_ + t * 16 + q * 4) * 128.0f;
        c1q[t] = *(const floatx4*)(W1 + 1 * HID_ + t * 16 + q * 4) * 128.0f;
    }

    // ---- per-row x/b1 part of the LUT index, exact f32, 4 rows:
    //      ax[it][t] = 128*(x0*W1[2][H] + x1*W1[3][H] + b1[H]) + 1024.5 ----
    floatx4 ax[4][4];
    #pragma unroll
    for (int t = 0; t < 4; ++t) {
        const floatx4 w2v = *(const floatx4*)(W1 + 2 * HID_ + t * 16 + q * 4);
        const floatx4 w3v = *(const floatx4*)(W1 + 3 * HID_ + t * 16 + q * 4);
        const floatx4 b1v = *(const floatx4*)(b1 + t * 16 + q * 4);
        #pragma unroll
        for (int it = 0; it < 4; ++it) {
            const float2 xv = *(const float2*)(x + (size_t)(row0 + it) * 2);
            const floatx4 pre = __builtin_elementwise_fma(splat4(xv.x), w2v,
                                __builtin_elementwise_fma(splat4(xv.y), w3v, b1v));
            ax[it][t] = __builtin_elementwise_fma(pre, splat4(128.0f), splat4(1024.5f));
        }
    }

    // ---- W2 A-fragment with layer-1-layout re-index (R13-validated) ----
    short8 w2f[2];
    #pragma unroll
    for (int ch = 0; ch < 2; ++ch)
        #pragma unroll
        for (int jj = 0; jj < 8; ++jj) {
            const int H = (ch * 2 + (jj >> 2)) * 16 + q * 4 + (jj & 3);
            w2f[ch][jj] = f2bf(W2[H * DOUT_ + nlo]);
        }
    const floatx4 b2r = *(const floatx4*)(b2 + q * 4);

    // ---- BURST: fv -> LDS slab (no VGPR cost); y (all lanes, f32) + w -> regs ----
    float2 yv2[8]; float sw[8];
    #pragma unroll
    for (int P = 0; P < 8; ++P) {
        const int rv  = raw[P];
        const int vld = rv >= 0;
        const int bn  = bbase + (vld ? rv : 0);
        gload_lds16(f_y + (size_t)bn * 16 + q * 4, &stg[wid][P][0]);
        const float wv_ = weights[bn];
        sw[P] = vld ? wv_ : 0.0f;
        yv2[P] = *(const float2*)(y + (size_t)bn * 2);   // finite garbage if invalid; killed by sw=0
    }

    // Single drain: __syncthreads waits vmcnt(0)+lgkmcnt(0) (burst complete,
    // LUT visible). sched_barrier keeps compute below it.
    __syncthreads();
    __builtin_amdgcn_sched_barrier(0);

    float partial[4] = {0.f, 0.f, 0.f, 0.f};
    #pragma unroll
    for (int it = 0; it < 4; ++it) {
        const int pa = 2 * it, pb = 2 * it + 1;

        // fv slices for both half-phases (ds_read_b128, issued up front)
        const floatx4 fva = *(const floatx4*)&stg[wid][pa][lane * 4];
        const floatx4 fvb = *(const floatx4*)&stg[wid][pb][lane * 4];

        const float y0a = yv2[pa].x, y1a = yv2[pa].y;
        const float y0b = yv2[pb].x, y1b = yv2[pb].y;

        // ---- layer 1 (rank-4, exact f32): idx = y0*c0 + y1*c1 + ax;
        //      then clamp -> LUT -> pack. Two independent chains. ----
        unsigned hwa[8], hwb[8];
        #pragma unroll
        for (int t = 0; t < 4; ++t) {
            floatx4 ia = __builtin_elementwise_fma(splat4(y0a), c0q[t],
                         __builtin_elementwise_fma(splat4(y1a), c1q[t], ax[it][t]));
            floatx4 ib = __builtin_elementwise_fma(splat4(y0b), c0q[t],
                         __builtin_elementwise_fma(splat4(y1b), c1q[t], ax[it][t]));
            ia = __builtin_elementwise_min(
                     __builtin_elementwise_max(ia, splat4(0.0f)), splat4(2047.0f));
            ib = __builtin_elementwise_min(
                     __builtin_elementwise_max(ib, splat4(0.0f)), splat4(2047.0f));
            const unsigned short a0 = lut[(unsigned)ia[0]];
            const unsigned short a1 = lut[(unsigned)ia[1]];
            const unsigned short a2 = lut[(unsigned)ia[2]];
            const unsigned short a3 = lut[(unsigned)ia[3]];
            const unsigned short c0 = lut[(unsigned)ib[0]];
            const unsigned short c1 = lut[(unsigned)ib[1]];
            const unsigned short c2 = lut[(unsigned)ib[2]];
            const unsigned short c3 = lut[(unsigned)ib[3]];
            hwa[t * 2 + 0] = (unsigned)a0 | ((unsigned)a1 << 16);
            hwa[t * 2 + 1] = (unsigned)a2 | ((unsigned)a3 << 16);
            hwb[t * 2 + 0] = (unsigned)c0 | ((unsigned)c1 << 16);
            hwb[t * 2 + 1] = (unsigned)c2 | ((unsigned)c3 << 16);
        }
        const short8 hf0a = __builtin_bit_cast(short8, (uint4v){hwa[0], hwa[1], hwa[2], hwa[3]});
        const short8 hf1a = __builtin_bit_cast(short8, (uint4v){hwa[4], hwa[5], hwa[6], hwa[7]});
        const short8 hf0b = __builtin_bit_cast(short8, (uint4v){hwb[0], hwb[1], hwb[2], hwb[3]});
        const short8 hf1b = __builtin_bit_cast(short8, (uint4v){hwb[4], hwb[5], hwb[6], hwb[7]});

        // ---- layer 2: both chains interleaved (only MFMAs left) ----
        floatx4 acca = b2r, accb = b2r;
        acca = __builtin_amdgcn_mfma_f32_16x16x32_bf16(w2f[0], hf0a, acca, 0, 0, 0);
        accb = __builtin_amdgcn_mfma_f32_16x16x32_bf16(w2f[0], hf0b, accb, 0, 0, 0);
        acca = __builtin_amdgcn_mfma_f32_16x16x32_bf16(w2f[1], hf1a, acca, 0, 0, 0);
        accb = __builtin_amdgcn_mfma_f32_16x16x32_bf16(w2f[1], hf1b, accb, 0, 0, 0);

        // ---- accumulate both half-phases, reduce over 16 lanes, store row ----
        const float sa = sw[pa], sb = sw[pb];
        #pragma unroll
        for (int r = 0; r < 4; ++r) {
            partial[r] = fmaf(acca[r], fva[r] * sa, partial[r]);
            partial[r] = fmaf(accb[r], fvb[r] * sb, partial[r]);
        }
        #pragma unroll
        for (int r = 0; r < 4; ++r) partial[r] = row16_sum(partial[r]);
        if (nlo == 15) {
            floatx4 o = {partial[0], partial[1], partial[2], partial[3]};
            *(floatx4*)(out + (size_t)(row0 + it) * DOUT_ + q * 4) = o;
        }
        #pragma unroll
        for (int r = 0; r < 4; ++r) partial[r] = 0.f;
    }
}

extern "C" void kernel_launch(void* const* d_in, const int* in_sizes, int n_in,
                              void* d_out, int out_size, void* d_ws, size_t ws_size,
                              hipStream_t stream) {
    const float* y   = (const float*)d_in[0];
    const float* x   = (const float*)d_in[1];
    const float* f_y = (const float*)d_in[2];
    const float* w   = (const float*)d_in[3];
    const float* W1  = (const float*)d_in[4];
    const float* b1  = (const float*)d_in[5];
    const float* W2  = (const float*)d_in[6];
    const float* b2  = (const float*)d_in[7];
    const int*   nbr = (const int*)d_in[8];
    float* out = (float*)d_out;

    // Single dispatch. 2048 blocks: 256 per batch (16 rows/block),
    // batch = blk & 7 -> XCD pin.
    dim3 grid(B_ * M_ / 16), block(256);
    hipLaunchKernelGGL(it_kernel, grid, block, 0, stream,
                       y, x, f_y, w, W1, b1, W2, b2, nbr, out);
}